// Round 1
// baseline (1009.294 us; speedup 1.0000x reference)
//
#include <hip/hip_runtime.h>
#include <math.h>

#define H 128
#define DXI 8
#define NNODES 100000
#define NEDGES 1000000
#define NDOM 32768
#define NBND 8192
#define NPTS (NDOM + NBND)
#define INV_RE 1.45e-05f

// d_out layout (floats): out_sup[300000] | continuity[32768] | momx[32768] | momy[32768] | boundary[8192]
#define CONT_OFF (NNODES * 3)
#define MOMX_OFF (CONT_OFF + NDOM)
#define MOMY_OFF (MOMX_OFF + NDOM)
#define BND_OFF  (MOMY_OFF + NDOM)

// ---------------------------------------------------------------------------
// Edge kernel: recompute node_h[src] per edge (x gather is 32B vs 512B for a
// materialized node_h row), multiply by (ea@We), atomicAdd into agg[dst].
// 256 threads = 2 edge-groups of 128 channels.
// ---------------------------------------------------------------------------
__global__ __launch_bounds__(256) void edge_kernel(
    const float* __restrict__ x, const float* __restrict__ pos,
    const int* __restrict__ eidx, const float* __restrict__ eattr,
    const float* __restrict__ Wx, const float* __restrict__ Wp,
    const float* __restrict__ We, float* __restrict__ agg)
{
    const int ch  = threadIdx.x & (H - 1);
    const int sub = threadIdx.x >> 7;   // 0 or 1

    float wx[DXI];
#pragma unroll
    for (int k = 0; k < DXI; ++k) wx[k] = Wx[k * H + ch];
    const float wp0 = Wp[ch],     wp1 = Wp[H + ch];
    const float we0 = We[ch],     we1 = We[H + ch], we2 = We[2 * H + ch];

    for (int e = blockIdx.x * 2 + sub; e < NEDGES; e += gridDim.x * 2) {
        const int s = eidx[e];
        const int d = eidx[NEDGES + e];
        const float* xr = x + (size_t)s * DXI;
        float a = fmaf(wp0, pos[(size_t)s * 3], wp1 * pos[(size_t)s * 3 + 1]);
#pragma unroll
        for (int k = 0; k < DXI; ++k) a = fmaf(xr[k], wx[k], a);
        const float nh = tanhf(a);
        const float* er = eattr + (size_t)e * 4;
        const float w = fmaf(er[0], we0, fmaf(er[1], we1, er[3] * we2));
        atomicAdd(&agg[(size_t)d * H + ch], nh * w);
    }
}

// ---------------------------------------------------------------------------
// Node kernel: h = tanh(node_h + agg), out_sup = h@Wout, ctx partial sums.
// 128 threads = channels; one node at a time per block, grid-stride.
// ---------------------------------------------------------------------------
__global__ __launch_bounds__(128) void node_kernel(
    const float* __restrict__ x, const float* __restrict__ pos,
    const float* __restrict__ Wx, const float* __restrict__ Wp,
    const float* __restrict__ Wout, const float* __restrict__ agg,
    float* __restrict__ out_sup, float* __restrict__ ctx_sum)
{
    const int ch = threadIdx.x;
    float wx[DXI];
#pragma unroll
    for (int k = 0; k < DXI; ++k) wx[k] = Wx[k * H + ch];
    const float wp0 = Wp[ch], wp1 = Wp[H + ch];
    const float wo0 = Wout[ch * 3], wo1 = Wout[ch * 3 + 1], wo2 = Wout[ch * 3 + 2];

    __shared__ float red[2][3];
    float ctx_acc = 0.f;

    for (int n = blockIdx.x; n < NNODES; n += gridDim.x) {
        const float* xr = x + (size_t)n * DXI;
        float a = fmaf(wp0, pos[(size_t)n * 3], wp1 * pos[(size_t)n * 3 + 1]);
#pragma unroll
        for (int k = 0; k < DXI; ++k) a = fmaf(xr[k], wx[k], a);
        const float nh = tanhf(a);
        const float h = tanhf(nh + agg[(size_t)n * H + ch]);
        ctx_acc += h;

        float p0 = h * wo0, p1 = h * wo1, p2 = h * wo2;
#pragma unroll
        for (int m = 32; m; m >>= 1) {
            p0 += __shfl_xor(p0, m);
            p1 += __shfl_xor(p1, m);
            p2 += __shfl_xor(p2, m);
        }
        const int wave = ch >> 6;
        if ((ch & 63) == 0) { red[wave][0] = p0; red[wave][1] = p1; red[wave][2] = p2; }
        __syncthreads();
        if (ch == 0) {
            out_sup[(size_t)n * 3 + 0] = red[0][0] + red[1][0];
            out_sup[(size_t)n * 3 + 1] = red[0][1] + red[1][1];
            out_sup[(size_t)n * 3 + 2] = red[0][2] + red[1][2];
        }
        __syncthreads();
    }
    atomicAdd(&ctx_sum[ch], ctx_acc);
}

// ---------------------------------------------------------------------------
// ctx finalize + c = b1 + ctx @ W1[2:,:]   (1 block, 128 threads)
// ---------------------------------------------------------------------------
__global__ __launch_bounds__(128) void ctx_kernel(
    const float* __restrict__ ctx_sum, const float* __restrict__ W1,
    const float* __restrict__ b1, float* __restrict__ cvec)
{
    __shared__ float ctx[H];
    const int ch = threadIdx.x;
    ctx[ch] = ctx_sum[ch] * (1.0f / (float)NNODES);
    __syncthreads();
    float acc = b1[ch];
    for (int k = 0; k < H; ++k) acc = fmaf(ctx[k], W1[(size_t)(2 + k) * H + ch], acc);
    cvec[ch] = acc;
}

// ---------------------------------------------------------------------------
// Sampling kernel: closed-form forward-mode value/grad/Hessian-diag of the
// 2-layer MLP. W2 staged in LDS once per block; 5 mat-vecs per point.
// ---------------------------------------------------------------------------
__global__ __launch_bounds__(128) void samp_kernel(
    const float* __restrict__ dom, const float* __restrict__ bnd,
    const int* __restrict__ bidx,
    const float* __restrict__ x, const float* __restrict__ xmask,
    const float* __restrict__ W1, const float* __restrict__ cvec,
    const float* __restrict__ W2, const float* __restrict__ b2,
    const float* __restrict__ W3, float* __restrict__ out)
{
    __shared__ float  W2s[H * H];      // 64 KB
    __shared__ float4 vA[H];           // {h1, g1x, g1y, s1xx}
    __shared__ float  vB[H];           // s1yy
    __shared__ float  red[2][13];

    const int ch = threadIdx.x;
    for (int i = ch; i < H * H; i += 128) W2s[i] = W2[i];

    const float A0 = W1[ch], A1 = W1[H + ch];
    const float cc = cvec[ch], bb = b2[ch];
    const float w30 = W3[ch * 3], w31 = W3[ch * 3 + 1], w32 = W3[ch * 3 + 2];
    __syncthreads();

    for (int p = blockIdx.x; p < NPTS; p += gridDim.x) {
        float spx, spy;
        if (p < NDOM) { spx = dom[(size_t)p * 2]; spy = dom[(size_t)p * 2 + 1]; }
        else { spx = bnd[(size_t)(p - NDOM) * 2]; spy = bnd[(size_t)(p - NDOM) * 2 + 1]; }

        const float a1 = fmaf(spx, A0, fmaf(spy, A1, cc));
        const float h1 = tanhf(a1);
        const float t1 = 1.f - h1 * h1;
        const float g1x = t1 * A0, g1y = t1 * A1;
        const float m2 = -2.f * h1 * t1;
        vA[ch] = make_float4(h1, g1x, g1y, m2 * A0 * A0);
        vB[ch] = m2 * A1 * A1;
        __syncthreads();

        float a2 = bb, d2x = 0.f, d2y = 0.f, e2xx = 0.f, e2yy = 0.f;
#pragma unroll 4
        for (int k = 0; k < H; ++k) {
            const float4 va = vA[k];
            const float  vb = vB[k];
            const float  w  = W2s[k * H + ch];
            a2   = fmaf(va.x, w, a2);
            d2x  = fmaf(va.y, w, d2x);
            d2y  = fmaf(va.z, w, d2y);
            e2xx = fmaf(va.w, w, e2xx);
            e2yy = fmaf(vb,   w, e2yy);
        }
        const float h2 = tanhf(a2);
        const float t2 = 1.f - h2 * h2;
        const float gx = t2 * d2x, gy = t2 * d2y;
        const float hxx = fmaf(-2.f * h2 * gx, d2x, t2 * e2xx);
        const float hyy = fmaf(-2.f * h2 * gy, d2y, t2 * e2yy);

        float pr[13];
        pr[0] = h2 * w30;  pr[1] = h2 * w31;  pr[2] = h2 * w32;
        pr[3] = gx * w30;  pr[4] = gx * w31;  pr[5] = gx * w32;
        pr[6] = gy * w30;  pr[7] = gy * w31;  pr[8] = gy * w32;
        pr[9] = hxx * w30; pr[10] = hxx * w31;
        pr[11] = hyy * w30; pr[12] = hyy * w31;
#pragma unroll
        for (int m = 32; m; m >>= 1)
#pragma unroll
            for (int i = 0; i < 13; ++i) pr[i] += __shfl_xor(pr[i], m);

        const int wave = ch >> 6;
        if ((ch & 63) == 0)
#pragma unroll
            for (int i = 0; i < 13; ++i) red[wave][i] = pr[i];
        __syncthreads();

        if (ch == 0) {
            const float u   = red[0][0] + red[1][0];
            const float v   = red[0][1] + red[1][1];
            const float pp  = red[0][2] + red[1][2];
            const float ux  = red[0][3] + red[1][3];
            const float vx  = red[0][4] + red[1][4];
            const float px  = red[0][5] + red[1][5];
            const float uy  = red[0][6] + red[1][6];
            const float vy  = red[0][7] + red[1][7];
            const float py  = red[0][8] + red[1][8];
            const float uxx = red[0][9] + red[1][9];
            const float vxx = red[0][10] + red[1][10];
            const float uyy = red[0][11] + red[1][11];
            const float vyy = red[0][12] + red[1][12];
            if (p < NDOM) {
                out[CONT_OFF + p] = ux + vy;
                out[MOMX_OFF + p] = fmaf(u, ux, fmaf(v, uy, px)) - (uxx + uyy) * INV_RE;
                out[MOMY_OFF + p] = fmaf(u, vx, fmaf(v, vy, py)) - (vxx + vyy) * INV_RE;
            } else {
                const int i = p - NDOM;
                const int idx = bidx[i];
                const float* xb = x + (size_t)idx * DXI;
                const float* mm = xmask + (size_t)idx * 6;
                const float tx = xb[0], ty = xb[1];
                const float nx = -ty, ny = tx;
                const float r_vt = fabsf(tx * u + ty * v - xb[2]) * mm[1];
                const float r_vn = fabsf(nx * u + ny * v - xb[3]) * mm[2];
                const float r_p  = fabsf(pp - xb[4]) * mm[3];
                const float r_dv = fabsf(nx * ux + ny * vy - xb[5]) * mm[4];
                const float r_dp = fabsf(nx * px + ny * py - xb[6]) * mm[5];
                const float c = mm[1] + mm[2] + mm[3] + mm[4] + mm[5];
                out[BND_OFF + i] = (r_vt + r_vn + r_p + r_dv + r_dp) / c;
            }
        }
    }
}

extern "C" void kernel_launch(void* const* d_in, const int* in_sizes, int n_in,
                              void* d_out, int out_size, void* d_ws, size_t ws_size,
                              hipStream_t stream) {
    const float* x     = (const float*)d_in[0];
    const float* xmask = (const float*)d_in[1];
    const int*   eidx  = (const int*)d_in[2];
    const float* eattr = (const float*)d_in[3];
    const float* pos   = (const float*)d_in[4];
    const float* dom   = (const float*)d_in[6];
    const float* bnd   = (const float*)d_in[7];
    const int*   bidx  = (const int*)d_in[8];
    const float* Wx    = (const float*)d_in[9];
    const float* Wp    = (const float*)d_in[10];
    const float* We    = (const float*)d_in[11];
    const float* Wout  = (const float*)d_in[12];
    const float* W1    = (const float*)d_in[13];
    const float* b1    = (const float*)d_in[14];
    const float* W2    = (const float*)d_in[15];
    const float* b2    = (const float*)d_in[16];
    const float* W3    = (const float*)d_in[17];

    float* out = (float*)d_out;
    float* ws  = (float*)d_ws;

    float* agg     = ws;                         // NNODES*H floats
    float* ctx_sum = ws + (size_t)NNODES * H;    // H floats
    float* cvec    = ctx_sum + H;                // H floats

    hipMemsetAsync(agg, 0, ((size_t)NNODES * H + H) * sizeof(float), stream);

    edge_kernel<<<4096, 256, 0, stream>>>(x, pos, eidx, eattr, Wx, Wp, We, agg);
    node_kernel<<<2048, 128, 0, stream>>>(x, pos, Wx, Wp, Wout, agg, out, ctx_sum);
    ctx_kernel<<<1, H, 0, stream>>>(ctx_sum, W1, b1, cvec);
    samp_kernel<<<1024, 128, 0, stream>>>(dom, bnd, bidx, x, xmask, W1, cvec, W2, b2, W3, out);
}

// Round 2
// 717.632 us; speedup vs baseline: 1.4064x; 1.4064x over previous
//
#include <hip/hip_runtime.h>
#include <math.h>

#define H 128
#define DXI 8
#define NNODES 100000
#define NEDGES 1000000
#define NDOM 32768
#define NBND 8192
#define NPTS (NDOM + NBND)
#define INV_RE 1.45e-05f

// d_out layout (floats): out_sup[300000] | continuity[32768] | momx[32768] | momy[32768] | boundary[8192]
#define CONT_OFF (NNODES * 3)
#define MOMX_OFF (CONT_OFF + NDOM)
#define MOMY_OFF (MOMX_OFF + NDOM)
#define BND_OFF  (MOMY_OFF + NDOM)

// fast tanh: 1 - 2/(exp2(2x*log2e)+1). Saturates correctly at +/-inf.
__device__ __forceinline__ float fast_tanh(float x) {
    const float e = __builtin_amdgcn_exp2f(x * 2.88539008f);
    return fmaf(-2.f, __builtin_amdgcn_rcpf(e + 1.f), 1.f);
}

// ---------------------------------------------------------------------------
// Edge kernel: recompute node_h[src] per edge, multiply by (ea@We),
// atomicAdd into agg[dst]. Edge index is wave-uniform -> scalar loads for
// eidx/x/pos/eattr via readfirstlane.
// ---------------------------------------------------------------------------
__global__ __launch_bounds__(256) void edge_kernel(
    const float* __restrict__ x, const float* __restrict__ pos,
    const int* __restrict__ eidx, const float* __restrict__ eattr,
    const float* __restrict__ Wx, const float* __restrict__ Wp,
    const float* __restrict__ We, float* __restrict__ agg)
{
    const int ch  = threadIdx.x & (H - 1);
    const int sub = threadIdx.x >> 7;   // 0 or 1 (wave-uniform)

    float wx[DXI];
#pragma unroll
    for (int k = 0; k < DXI; ++k) wx[k] = Wx[k * H + ch];
    const float wp0 = Wp[ch],     wp1 = Wp[H + ch];
    const float we0 = We[ch],     we1 = We[H + ch], we2 = We[2 * H + ch];

    for (int e = blockIdx.x * 2 + sub; e < NEDGES; e += gridDim.x * 2) {
        const int eu = __builtin_amdgcn_readfirstlane(e);
        const int s  = eidx[eu];
        const int d  = eidx[NEDGES + eu];
        const float* xr = x + (size_t)s * DXI;
        float a = fmaf(wp0, pos[(size_t)s * 3], wp1 * pos[(size_t)s * 3 + 1]);
#pragma unroll
        for (int k = 0; k < DXI; ++k) a = fmaf(xr[k], wx[k], a);
        const float nh = fast_tanh(a);
        const float* er = eattr + (size_t)eu * 4;
        const float w = fmaf(er[0], we0, fmaf(er[1], we1, er[3] * we2));
        atomicAdd(&agg[(size_t)d * H + ch], nh * w);
    }
}

// ---------------------------------------------------------------------------
// Node kernel: h = tanh(node_h + agg), out_sup = h@Wout, ctx partial sums.
// ---------------------------------------------------------------------------
__global__ __launch_bounds__(128) void node_kernel(
    const float* __restrict__ x, const float* __restrict__ pos,
    const float* __restrict__ Wx, const float* __restrict__ Wp,
    const float* __restrict__ Wout, const float* __restrict__ agg,
    float* __restrict__ out_sup, float* __restrict__ ctx_sum)
{
    const int ch = threadIdx.x;
    float wx[DXI];
#pragma unroll
    for (int k = 0; k < DXI; ++k) wx[k] = Wx[k * H + ch];
    const float wp0 = Wp[ch], wp1 = Wp[H + ch];
    const float wo0 = Wout[ch * 3], wo1 = Wout[ch * 3 + 1], wo2 = Wout[ch * 3 + 2];

    __shared__ float red[2][3];
    float ctx_acc = 0.f;

    for (int n = blockIdx.x; n < NNODES; n += gridDim.x) {
        const float* xr = x + (size_t)n * DXI;
        float a = fmaf(wp0, pos[(size_t)n * 3], wp1 * pos[(size_t)n * 3 + 1]);
#pragma unroll
        for (int k = 0; k < DXI; ++k) a = fmaf(xr[k], wx[k], a);
        const float nh = fast_tanh(a);
        const float h = fast_tanh(nh + agg[(size_t)n * H + ch]);
        ctx_acc += h;

        float p0 = h * wo0, p1 = h * wo1, p2 = h * wo2;
#pragma unroll
        for (int m = 32; m; m >>= 1) {
            p0 += __shfl_xor(p0, m);
            p1 += __shfl_xor(p1, m);
            p2 += __shfl_xor(p2, m);
        }
        const int wave = ch >> 6;
        if ((ch & 63) == 0) { red[wave][0] = p0; red[wave][1] = p1; red[wave][2] = p2; }
        __syncthreads();
        if (ch == 0) {
            out_sup[(size_t)n * 3 + 0] = red[0][0] + red[1][0];
            out_sup[(size_t)n * 3 + 1] = red[0][1] + red[1][1];
            out_sup[(size_t)n * 3 + 2] = red[0][2] + red[1][2];
        }
        __syncthreads();
    }
    atomicAdd(&ctx_sum[ch], ctx_acc);
}

// ---------------------------------------------------------------------------
// ctx finalize: cvec = b1 + ctx@W1[2:,:]  and per-k table for samp_kernel:
// tab[k][0..4] = {A0, A1, cc, A0^2, A1^2}  (padded to 8 floats)
// ---------------------------------------------------------------------------
__global__ __launch_bounds__(128) void ctx_kernel(
    const float* __restrict__ ctx_sum, const float* __restrict__ W1,
    const float* __restrict__ b1, float* __restrict__ tab)
{
    __shared__ float ctx[H];
    const int ch = threadIdx.x;
    ctx[ch] = ctx_sum[ch] * (1.0f / (float)NNODES);
    __syncthreads();
    float acc = b1[ch];
    for (int k = 0; k < H; ++k) acc = fmaf(ctx[k], W1[(size_t)(2 + k) * H + ch], acc);
    const float A0 = W1[ch], A1 = W1[H + ch];
    tab[ch * 8 + 0] = A0;
    tab[ch * 8 + 1] = A1;
    tab[ch * 8 + 2] = acc;
    tab[ch * 8 + 3] = A0 * A0;
    tab[ch * 8 + 4] = A1 * A1;
    tab[ch * 8 + 5] = 0.f;
    tab[ch * 8 + 6] = 0.f;
    tab[ch * 8 + 7] = 0.f;
}

// ---------------------------------------------------------------------------
// Sampling kernel v2: zero LDS. Thread = (point, 16-output-channel group).
// Layer-1 quantities recomputed per k from registers + uniform tab row
// (scalar loads). Inner loop: 80 register FMAs per k. 8-thread shfl reduce.
// Block 256 = 32 points x 8 jgroups. Grid 1280 -> exactly 40960 points.
// ---------------------------------------------------------------------------
__global__ __launch_bounds__(256, 2) void samp_kernel(
    const float* __restrict__ dom, const float* __restrict__ bnd,
    const int* __restrict__ bidx,
    const float* __restrict__ x, const float* __restrict__ xmask,
    const float* __restrict__ tab,
    const float* __restrict__ W2, const float* __restrict__ b2,
    const float* __restrict__ W3, float* __restrict__ out)
{
    const int tid = threadIdx.x;
    const int jg  = tid & 7;          // 8 output-channel groups of 16
    const int pl  = tid >> 3;         // 32 points per block
    const int p   = blockIdx.x * 32 + pl;
    const int j0  = jg * 16;

    float spx, spy;
    if (p < NDOM) { spx = dom[(size_t)p * 2];          spy = dom[(size_t)p * 2 + 1]; }
    else          { spx = bnd[(size_t)(p - NDOM) * 2]; spy = bnd[(size_t)(p - NDOM) * 2 + 1]; }

    float a2[16], d2x[16], d2y[16], exx[16], eyy[16];
#pragma unroll
    for (int jj = 0; jj < 16; ++jj) {
        a2[jj] = b2[j0 + jj];
        d2x[jj] = 0.f; d2y[jj] = 0.f; exx[jj] = 0.f; eyy[jj] = 0.f;
    }

    for (int k = 0; k < H; ++k) {
        const float4 t4 = *(const float4*)(tab + (size_t)k * 8);
        const float A1s = tab[(size_t)k * 8 + 4];
        const float A0 = t4.x, A1 = t4.y, cc = t4.z, A0s = t4.w;

        const float a1 = fmaf(spx, A0, fmaf(spy, A1, cc));
        const float e  = __builtin_amdgcn_exp2f(a1 * 2.88539008f);
        const float h1 = fmaf(-2.f, __builtin_amdgcn_rcpf(e + 1.f), 1.f);
        const float t1 = fmaf(-h1, h1, 1.f);
        const float m2 = -2.f * h1 * t1;
        const float g1x = t1 * A0, g1y = t1 * A1;
        const float sxx = m2 * A0s, syy = m2 * A1s;

        const float4* wr = (const float4*)(W2 + (size_t)k * H + j0);
        float4 w4[4];
        w4[0] = wr[0]; w4[1] = wr[1]; w4[2] = wr[2]; w4[3] = wr[3];
        const float* wf = (const float*)w4;
#pragma unroll
        for (int jj = 0; jj < 16; ++jj) {
            const float w = wf[jj];
            a2[jj]  = fmaf(h1,  w, a2[jj]);
            d2x[jj] = fmaf(g1x, w, d2x[jj]);
            d2y[jj] = fmaf(g1y, w, d2y[jj]);
            exx[jj] = fmaf(sxx, w, exx[jj]);
            eyy[jj] = fmaf(syy, w, eyy[jj]);
        }
    }

    // epilogue: layer-2 nonlinearity + layer-3 contraction (partial over 16 j)
    float r[13];
#pragma unroll
    for (int i = 0; i < 13; ++i) r[i] = 0.f;
#pragma unroll
    for (int jj = 0; jj < 16; ++jj) {
        const float h2 = fast_tanh(a2[jj]);
        const float t2 = fmaf(-h2, h2, 1.f);
        const float gx = t2 * d2x[jj];
        const float gy = t2 * d2y[jj];
        const float hxx = fmaf(-2.f * h2 * gx, d2x[jj], t2 * exx[jj]);
        const float hyy = fmaf(-2.f * h2 * gy, d2y[jj], t2 * eyy[jj]);
        const int j = j0 + jj;
        const float w30 = W3[j * 3], w31 = W3[j * 3 + 1], w32 = W3[j * 3 + 2];
        r[0]  = fmaf(h2, w30, r[0]);   r[1]  = fmaf(h2, w31, r[1]);   r[2] = fmaf(h2, w32, r[2]);
        r[3]  = fmaf(gx, w30, r[3]);   r[4]  = fmaf(gx, w31, r[4]);   r[5] = fmaf(gx, w32, r[5]);
        r[6]  = fmaf(gy, w30, r[6]);   r[7]  = fmaf(gy, w31, r[7]);   r[8] = fmaf(gy, w32, r[8]);
        r[9]  = fmaf(hxx, w30, r[9]);  r[10] = fmaf(hxx, w31, r[10]);
        r[11] = fmaf(hyy, w30, r[11]); r[12] = fmaf(hyy, w31, r[12]);
    }

    // reduce across the 8 jg threads (lanes pl*8+jg are contiguous in-wave)
#pragma unroll
    for (int m = 1; m < 8; m <<= 1)
#pragma unroll
        for (int i = 0; i < 13; ++i) r[i] += __shfl_xor(r[i], m);

    if (jg == 0) {
        const float u = r[0], v = r[1], pp = r[2];
        const float ux = r[3], vx = r[4], px = r[5];
        const float uy = r[6], vy = r[7], py = r[8];
        const float uxx = r[9], vxx = r[10], uyy = r[11], vyy = r[12];
        if (p < NDOM) {
            out[CONT_OFF + p] = ux + vy;
            out[MOMX_OFF + p] = fmaf(u, ux, fmaf(v, uy, px)) - (uxx + uyy) * INV_RE;
            out[MOMY_OFF + p] = fmaf(u, vx, fmaf(v, vy, py)) - (vxx + vyy) * INV_RE;
        } else {
            const int i = p - NDOM;
            const int idx = bidx[i];
            const float* xb = x + (size_t)idx * DXI;
            const float* mm = xmask + (size_t)idx * 6;
            const float tx = xb[0], ty = xb[1];
            const float nx = -ty, ny = tx;
            const float r_vt = fabsf(tx * u + ty * v - xb[2]) * mm[1];
            const float r_vn = fabsf(nx * u + ny * v - xb[3]) * mm[2];
            const float r_p  = fabsf(pp - xb[4]) * mm[3];
            const float r_dv = fabsf(nx * ux + ny * vy - xb[5]) * mm[4];
            const float r_dp = fabsf(nx * px + ny * py - xb[6]) * mm[5];
            const float c = mm[1] + mm[2] + mm[3] + mm[4] + mm[5];
            out[BND_OFF + i] = (r_vt + r_vn + r_p + r_dv + r_dp) / c;
        }
    }
}

extern "C" void kernel_launch(void* const* d_in, const int* in_sizes, int n_in,
                              void* d_out, int out_size, void* d_ws, size_t ws_size,
                              hipStream_t stream) {
    const float* x     = (const float*)d_in[0];
    const float* xmask = (const float*)d_in[1];
    const int*   eidx  = (const int*)d_in[2];
    const float* eattr = (const float*)d_in[3];
    const float* pos   = (const float*)d_in[4];
    const float* dom   = (const float*)d_in[6];
    const float* bnd   = (const float*)d_in[7];
    const int*   bidx  = (const int*)d_in[8];
    const float* Wx    = (const float*)d_in[9];
    const float* Wp    = (const float*)d_in[10];
    const float* We    = (const float*)d_in[11];
    const float* Wout  = (const float*)d_in[12];
    const float* W1    = (const float*)d_in[13];
    const float* b1    = (const float*)d_in[14];
    const float* W2    = (const float*)d_in[15];
    const float* b2    = (const float*)d_in[16];
    const float* W3    = (const float*)d_in[17];

    float* out = (float*)d_out;
    float* ws  = (float*)d_ws;

    float* agg     = ws;                         // NNODES*H floats
    float* ctx_sum = ws + (size_t)NNODES * H;    // H floats
    float* tab     = ctx_sum + H;                // H*8 floats

    hipMemsetAsync(agg, 0, ((size_t)NNODES * H + H) * sizeof(float), stream);

    edge_kernel<<<4096, 256, 0, stream>>>(x, pos, eidx, eattr, Wx, Wp, We, agg);
    node_kernel<<<2048, 128, 0, stream>>>(x, pos, Wx, Wp, Wout, agg, out, ctx_sum);
    ctx_kernel<<<1, H, 0, stream>>>(ctx_sum, W1, b1, tab);
    samp_kernel<<<1280, 256, 0, stream>>>(dom, bnd, bidx, x, xmask, tab, W2, b2, W3, out);
}

// Round 3
// 676.447 us; speedup vs baseline: 1.4921x; 1.0609x over previous
//
#include <hip/hip_runtime.h>
#include <math.h>

#define H 128
#define DXI 8
#define NNODES 100000
#define NEDGES 1000000
#define NDOM 32768
#define NBND 8192
#define NPTS (NDOM + NBND)
#define INV_RE 1.45e-05f

#define NSB ((NNODES + 1023) / 1024)   // scan blocks (1024 elems each) = 98

// d_out layout (floats): out_sup[300000] | continuity[32768] | momx[32768] | momy[32768] | boundary[8192]
#define CONT_OFF (NNODES * 3)
#define MOMX_OFF (CONT_OFF + NDOM)
#define MOMY_OFF (MOMX_OFF + NDOM)
#define BND_OFF  (MOMY_OFF + NDOM)

// fast tanh: 1 - 2/(exp2(2x*log2e)+1). Saturates correctly at +/-inf.
__device__ __forceinline__ float fast_tanh(float x) {
    const float e = __builtin_amdgcn_exp2f(x * 2.88539008f);
    return fmaf(-2.f, __builtin_amdgcn_rcpf(e + 1.f), 1.f);
}

// ---------------------------------------------------------------------------
// CSR build pass 1: histogram of destination nodes (int atomics, 400KB,
// L2-resident -> fast).
// ---------------------------------------------------------------------------
__global__ __launch_bounds__(256) void hist_kernel(
    const int* __restrict__ eidx, int* __restrict__ counts)
{
    const int* dst = eidx + NEDGES;
    for (int e = blockIdx.x * 256 + threadIdx.x; e < NEDGES; e += gridDim.x * 256)
        atomicAdd(&counts[dst[e]], 1);
}

// ---------------------------------------------------------------------------
// CSR build pass 2a: per-block exclusive scan (1024 elems/block), block
// totals to bsum.
// ---------------------------------------------------------------------------
__global__ __launch_bounds__(256) void scan1_kernel(
    const int* __restrict__ counts, int* __restrict__ excl, int* __restrict__ bsum)
{
    const int tid = threadIdx.x, b = blockIdx.x;
    const int base = b * 1024 + tid * 4;
    int v0 = 0, v1 = 0, v2 = 0, v3 = 0;
    if (base + 3 < NNODES) {
        const int4 t = *(const int4*)(counts + base);
        v0 = t.x; v1 = t.y; v2 = t.z; v3 = t.w;
    } else {
        if (base     < NNODES) v0 = counts[base];
        if (base + 1 < NNODES) v1 = counts[base + 1];
        if (base + 2 < NNODES) v2 = counts[base + 2];
        if (base + 3 < NNODES) v3 = counts[base + 3];
    }
    const int own = v0 + v1 + v2 + v3;
    int s = own;
    const int lane = tid & 63, wv = tid >> 6;
#pragma unroll
    for (int d = 1; d < 64; d <<= 1) {
        const int t = __shfl_up(s, d);
        if (lane >= d) s += t;
    }
    __shared__ int wsum[4];
    if (lane == 63) wsum[wv] = s;
    __syncthreads();
    int woff = 0;
    for (int w = 0; w < wv; ++w) woff += wsum[w];
    const int e0 = s - own + woff;
    const int e1 = e0 + v0, e2 = e1 + v1, e3 = e2 + v2;
    if (base + 3 < NNODES) {
        *(int4*)(excl + base) = make_int4(e0, e1, e2, e3);
    } else {
        if (base     < NNODES) excl[base]     = e0;
        if (base + 1 < NNODES) excl[base + 1] = e1;
        if (base + 2 < NNODES) excl[base + 2] = e2;
        if (base + 3 < NNODES) excl[base + 3] = e3;
    }
    if (tid == 0) bsum[b] = wsum[0] + wsum[1] + wsum[2] + wsum[3];
}

// ---------------------------------------------------------------------------
// CSR build pass 2b: exclusive scan of the NSB block totals (1 block).
// ---------------------------------------------------------------------------
__global__ __launch_bounds__(128) void scan2_kernel(int* __restrict__ bsum)
{
    const int tid = threadIdx.x;
    int v = (tid < NSB) ? bsum[tid] : 0;
    const int own = v;
    const int lane = tid & 63, wv = tid >> 6;
#pragma unroll
    for (int d = 1; d < 64; d <<= 1) {
        const int t = __shfl_up(v, d);
        if (lane >= d) v += t;
    }
    __shared__ int ws2[2];
    if (lane == 63) ws2[wv] = v;
    __syncthreads();
    if (wv == 1) v += ws2[0];
    if (tid < NSB) bsum[tid] = v - own;
}

// ---------------------------------------------------------------------------
// CSR build pass 2c: add block offsets; produce offsets[] and working
// cursor[] copy. Also set offsets[NNODES] = NEDGES.
// ---------------------------------------------------------------------------
__global__ __launch_bounds__(256) void scan3_kernel(
    int* __restrict__ offsets, int* __restrict__ cursor, const int* __restrict__ bsum)
{
    const int tid = threadIdx.x, b = blockIdx.x;
    const int base = b * 1024 + tid * 4;
    const int add = bsum[b];
    if (base + 3 < NNODES) {
        int4 t = *(const int4*)(offsets + base);
        t.x += add; t.y += add; t.z += add; t.w += add;
        *(int4*)(offsets + base) = t;
        *(int4*)(cursor + base) = t;
    } else {
        for (int i = 0; i < 4; ++i)
            if (base + i < NNODES) {
                const int t = offsets[base + i] + add;
                offsets[base + i] = t;
                cursor[base + i] = t;
            }
    }
    if (b == NSB - 1 && tid == 255) offsets[NNODES] = NEDGES;
}

// ---------------------------------------------------------------------------
// CSR build pass 3: scatter edge ids into dst-sorted order.
// ---------------------------------------------------------------------------
__global__ __launch_bounds__(256) void scatter_kernel(
    const int* __restrict__ eidx, int* __restrict__ cursor, int* __restrict__ csr)
{
    const int* dst = eidx + NEDGES;
    for (int e = blockIdx.x * 256 + threadIdx.x; e < NEDGES; e += gridDim.x * 256) {
        const int d = dst[e];
        const int slot = atomicAdd(&cursor[d], 1);
        csr[slot] = e;
    }
}

// ---------------------------------------------------------------------------
// Fused gather + node kernel: one WAVE per node; lane owns channels
// {lane, lane+64}. Register-accumulate incoming messages (recomputing
// node_h[src] from x/pos via uniform scalar loads), then h, out_sup, ctx.
// No f32 atomics except one ctx partial per thread at the end.
// ---------------------------------------------------------------------------
__global__ __launch_bounds__(256) void gather_node_kernel(
    const float* __restrict__ x, const float* __restrict__ pos,
    const int* __restrict__ eidx, const float* __restrict__ eattr,
    const float* __restrict__ Wx, const float* __restrict__ Wp,
    const float* __restrict__ We, const float* __restrict__ Wout,
    const int* __restrict__ offsets, const int* __restrict__ csr,
    float* __restrict__ out_sup, float* __restrict__ ctx_sum)
{
    const int lane = threadIdx.x & 63;
    const int wv   = threadIdx.x >> 6;          // 4 waves/block, 1 node each
    const int c0 = lane, c1 = lane + 64;

    float wxa[DXI], wxb[DXI];
#pragma unroll
    for (int k = 0; k < DXI; ++k) { wxa[k] = Wx[k * H + c0]; wxb[k] = Wx[k * H + c1]; }
    const float wp00 = Wp[c0], wp01 = Wp[H + c0];
    const float wp10 = Wp[c1], wp11 = Wp[H + c1];
    const float wea0 = We[c0], wea1 = We[H + c0], wea2 = We[2 * H + c0];
    const float web0 = We[c1], web1 = We[H + c1], web2 = We[2 * H + c1];
    const float woa0 = Wout[c0 * 3], woa1 = Wout[c0 * 3 + 1], woa2 = Wout[c0 * 3 + 2];
    const float wob0 = Wout[c1 * 3], wob1 = Wout[c1 * 3 + 1], wob2 = Wout[c1 * 3 + 2];

    float ctx0 = 0.f, ctx1 = 0.f;
    const int stride = gridDim.x * 4;

    for (int n = blockIdx.x * 4 + wv; n < NNODES; n += stride) {
        const int o0 = __builtin_amdgcn_readfirstlane(offsets[n]);
        const int o1 = __builtin_amdgcn_readfirstlane(offsets[n + 1]);
        float acc0 = 0.f, acc1 = 0.f;
        for (int i = o0; i < o1; ++i) {
            const int eid = __builtin_amdgcn_readfirstlane(csr[i]);
            const int s   = __builtin_amdgcn_readfirstlane(eidx[eid]);
            const float* xr = x + (size_t)s * DXI;
            const float px = pos[(size_t)s * 3], py = pos[(size_t)s * 3 + 1];
            float a0 = fmaf(wp00, px, wp01 * py);
            float a1 = fmaf(wp10, px, wp11 * py);
#pragma unroll
            for (int k = 0; k < DXI; ++k) {
                const float xv = xr[k];
                a0 = fmaf(xv, wxa[k], a0);
                a1 = fmaf(xv, wxb[k], a1);
            }
            const float* er = eattr + (size_t)eid * 4;
            const float e0 = er[0], e1 = er[1], e3 = er[3];
            const float w0 = fmaf(e0, wea0, fmaf(e1, wea1, e3 * wea2));
            const float w1 = fmaf(e0, web0, fmaf(e1, web1, e3 * web2));
            acc0 = fmaf(fast_tanh(a0), w0, acc0);
            acc1 = fmaf(fast_tanh(a1), w1, acc1);
        }
        // destination node features
        const float* xr = x + (size_t)n * DXI;
        const float px = pos[(size_t)n * 3], py = pos[(size_t)n * 3 + 1];
        float a0 = fmaf(wp00, px, wp01 * py);
        float a1 = fmaf(wp10, px, wp11 * py);
#pragma unroll
        for (int k = 0; k < DXI; ++k) {
            const float xv = xr[k];
            a0 = fmaf(xv, wxa[k], a0);
            a1 = fmaf(xv, wxb[k], a1);
        }
        const float h0 = fast_tanh(fast_tanh(a0) + acc0);
        const float h1 = fast_tanh(fast_tanh(a1) + acc1);
        ctx0 += h0; ctx1 += h1;

        float p0 = fmaf(h0, woa0, h1 * wob0);
        float p1 = fmaf(h0, woa1, h1 * wob1);
        float p2 = fmaf(h0, woa2, h1 * wob2);
#pragma unroll
        for (int m = 32; m; m >>= 1) {
            p0 += __shfl_xor(p0, m);
            p1 += __shfl_xor(p1, m);
            p2 += __shfl_xor(p2, m);
        }
        if (lane == 0) {
            out_sup[(size_t)n * 3 + 0] = p0;
            out_sup[(size_t)n * 3 + 1] = p1;
            out_sup[(size_t)n * 3 + 2] = p2;
        }
    }
    atomicAdd(&ctx_sum[c0], ctx0);
    atomicAdd(&ctx_sum[c1], ctx1);
}

// ---------------------------------------------------------------------------
// ctx finalize: tab[k] = {A0, A1, b1+ctx@W1[2:], A0^2, A1^2} (8-float rows)
// ---------------------------------------------------------------------------
__global__ __launch_bounds__(128) void ctx_kernel(
    const float* __restrict__ ctx_sum, const float* __restrict__ W1,
    const float* __restrict__ b1, float* __restrict__ tab)
{
    __shared__ float ctx[H];
    const int ch = threadIdx.x;
    ctx[ch] = ctx_sum[ch] * (1.0f / (float)NNODES);
    __syncthreads();
    float acc = b1[ch];
    for (int k = 0; k < H; ++k) acc = fmaf(ctx[k], W1[(size_t)(2 + k) * H + ch], acc);
    const float A0 = W1[ch], A1 = W1[H + ch];
    tab[ch * 8 + 0] = A0;
    tab[ch * 8 + 1] = A1;
    tab[ch * 8 + 2] = acc;
    tab[ch * 8 + 3] = A0 * A0;
    tab[ch * 8 + 4] = A1 * A1;
    tab[ch * 8 + 5] = 0.f;
    tab[ch * 8 + 6] = 0.f;
    tab[ch * 8 + 7] = 0.f;
}

// ---------------------------------------------------------------------------
// Sampling kernel: zero LDS. Thread = (point, 16-output-channel group).
// Layer-1 quantities recomputed per k from registers + uniform tab row
// (scalar loads). Inner loop: 80 register FMAs per k. 8-thread shfl reduce.
// ---------------------------------------------------------------------------
__global__ __launch_bounds__(256, 2) void samp_kernel(
    const float* __restrict__ dom, const float* __restrict__ bnd,
    const int* __restrict__ bidx,
    const float* __restrict__ x, const float* __restrict__ xmask,
    const float* __restrict__ tab,
    const float* __restrict__ W2, const float* __restrict__ b2,
    const float* __restrict__ W3, float* __restrict__ out)
{
    const int tid = threadIdx.x;
    const int jg  = tid & 7;          // 8 output-channel groups of 16
    const int pl  = tid >> 3;         // 32 points per block
    const int p   = blockIdx.x * 32 + pl;
    const int j0  = jg * 16;

    float spx, spy;
    if (p < NDOM) { spx = dom[(size_t)p * 2];          spy = dom[(size_t)p * 2 + 1]; }
    else          { spx = bnd[(size_t)(p - NDOM) * 2]; spy = bnd[(size_t)(p - NDOM) * 2 + 1]; }

    float a2[16], d2x[16], d2y[16], exx[16], eyy[16];
#pragma unroll
    for (int jj = 0; jj < 16; ++jj) {
        a2[jj] = b2[j0 + jj];
        d2x[jj] = 0.f; d2y[jj] = 0.f; exx[jj] = 0.f; eyy[jj] = 0.f;
    }

    for (int k = 0; k < H; ++k) {
        const float4 t4 = *(const float4*)(tab + (size_t)k * 8);
        const float A1s = tab[(size_t)k * 8 + 4];
        const float A0 = t4.x, A1 = t4.y, cc = t4.z, A0s = t4.w;

        const float a1 = fmaf(spx, A0, fmaf(spy, A1, cc));
        const float e  = __builtin_amdgcn_exp2f(a1 * 2.88539008f);
        const float h1 = fmaf(-2.f, __builtin_amdgcn_rcpf(e + 1.f), 1.f);
        const float t1 = fmaf(-h1, h1, 1.f);
        const float m2 = -2.f * h1 * t1;
        const float g1x = t1 * A0, g1y = t1 * A1;
        const float sxx = m2 * A0s, syy = m2 * A1s;

        const float4* wr = (const float4*)(W2 + (size_t)k * H + j0);
        float4 w4[4];
        w4[0] = wr[0]; w4[1] = wr[1]; w4[2] = wr[2]; w4[3] = wr[3];
        const float* wf = (const float*)w4;
#pragma unroll
        for (int jj = 0; jj < 16; ++jj) {
            const float w = wf[jj];
            a2[jj]  = fmaf(h1,  w, a2[jj]);
            d2x[jj] = fmaf(g1x, w, d2x[jj]);
            d2y[jj] = fmaf(g1y, w, d2y[jj]);
            exx[jj] = fmaf(sxx, w, exx[jj]);
            eyy[jj] = fmaf(syy, w, eyy[jj]);
        }
    }

    float r[13];
#pragma unroll
    for (int i = 0; i < 13; ++i) r[i] = 0.f;
#pragma unroll
    for (int jj = 0; jj < 16; ++jj) {
        const float h2 = fast_tanh(a2[jj]);
        const float t2 = fmaf(-h2, h2, 1.f);
        const float gx = t2 * d2x[jj];
        const float gy = t2 * d2y[jj];
        const float hxx = fmaf(-2.f * h2 * gx, d2x[jj], t2 * exx[jj]);
        const float hyy = fmaf(-2.f * h2 * gy, d2y[jj], t2 * eyy[jj]);
        const int j = j0 + jj;
        const float w30 = W3[j * 3], w31 = W3[j * 3 + 1], w32 = W3[j * 3 + 2];
        r[0]  = fmaf(h2, w30, r[0]);   r[1]  = fmaf(h2, w31, r[1]);   r[2] = fmaf(h2, w32, r[2]);
        r[3]  = fmaf(gx, w30, r[3]);   r[4]  = fmaf(gx, w31, r[4]);   r[5] = fmaf(gx, w32, r[5]);
        r[6]  = fmaf(gy, w30, r[6]);   r[7]  = fmaf(gy, w31, r[7]);   r[8] = fmaf(gy, w32, r[8]);
        r[9]  = fmaf(hxx, w30, r[9]);  r[10] = fmaf(hxx, w31, r[10]);
        r[11] = fmaf(hyy, w30, r[11]); r[12] = fmaf(hyy, w31, r[12]);
    }

#pragma unroll
    for (int m = 1; m < 8; m <<= 1)
#pragma unroll
        for (int i = 0; i < 13; ++i) r[i] += __shfl_xor(r[i], m);

    if (jg == 0) {
        const float u = r[0], v = r[1], pp = r[2];
        const float ux = r[3], vx = r[4], px = r[5];
        const float uy = r[6], vy = r[7], py = r[8];
        const float uxx = r[9], vxx = r[10], uyy = r[11], vyy = r[12];
        if (p < NDOM) {
            out[CONT_OFF + p] = ux + vy;
            out[MOMX_OFF + p] = fmaf(u, ux, fmaf(v, uy, px)) - (uxx + uyy) * INV_RE;
            out[MOMY_OFF + p] = fmaf(u, vx, fmaf(v, vy, py)) - (vxx + vyy) * INV_RE;
        } else {
            const int i = p - NDOM;
            const int idx = bidx[i];
            const float* xb = x + (size_t)idx * DXI;
            const float* mm = xmask + (size_t)idx * 6;
            const float tx = xb[0], ty = xb[1];
            const float nx = -ty, ny = tx;
            const float r_vt = fabsf(tx * u + ty * v - xb[2]) * mm[1];
            const float r_vn = fabsf(nx * u + ny * v - xb[3]) * mm[2];
            const float r_p  = fabsf(pp - xb[4]) * mm[3];
            const float r_dv = fabsf(nx * ux + ny * vy - xb[5]) * mm[4];
            const float r_dp = fabsf(nx * px + ny * py - xb[6]) * mm[5];
            const float c = mm[1] + mm[2] + mm[3] + mm[4] + mm[5];
            out[BND_OFF + i] = (r_vt + r_vn + r_p + r_dv + r_dp) / c;
        }
    }
}

extern "C" void kernel_launch(void* const* d_in, const int* in_sizes, int n_in,
                              void* d_out, int out_size, void* d_ws, size_t ws_size,
                              hipStream_t stream) {
    const float* x     = (const float*)d_in[0];
    const float* xmask = (const float*)d_in[1];
    const int*   eidx  = (const int*)d_in[2];
    const float* eattr = (const float*)d_in[3];
    const float* pos   = (const float*)d_in[4];
    const float* dom   = (const float*)d_in[6];
    const float* bnd   = (const float*)d_in[7];
    const int*   bidx  = (const int*)d_in[8];
    const float* Wx    = (const float*)d_in[9];
    const float* Wp    = (const float*)d_in[10];
    const float* We    = (const float*)d_in[11];
    const float* Wout  = (const float*)d_in[12];
    const float* W1    = (const float*)d_in[13];
    const float* b1    = (const float*)d_in[14];
    const float* W2    = (const float*)d_in[15];
    const float* b2    = (const float*)d_in[16];
    const float* W3    = (const float*)d_in[17];

    float* out = (float*)d_out;

    // workspace layout (all 16B-aligned)
    int*   counts  = (int*)d_ws;                    // NNODES
    int*   offsets = counts + NNODES;               // NNODES+8 (padded)
    int*   cursor  = offsets + NNODES + 8;          // NNODES
    int*   bsum    = cursor + NNODES;               // 128 (padded)
    int*   csr     = bsum + 128;                    // NEDGES
    float* ctx_sum = (float*)(csr + NEDGES);        // H
    float* tab     = ctx_sum + H;                   // H*8

    hipMemsetAsync(counts, 0, (size_t)NNODES * sizeof(int), stream);
    hipMemsetAsync(ctx_sum, 0, H * sizeof(float), stream);

    hist_kernel<<<512, 256, 0, stream>>>(eidx, counts);
    scan1_kernel<<<NSB, 256, 0, stream>>>(counts, offsets, bsum);
    scan2_kernel<<<1, 128, 0, stream>>>(bsum);
    scan3_kernel<<<NSB, 256, 0, stream>>>(offsets, cursor, bsum);
    scatter_kernel<<<512, 256, 0, stream>>>(eidx, cursor, csr);
    gather_node_kernel<<<2048, 256, 0, stream>>>(x, pos, eidx, eattr, Wx, Wp, We, Wout,
                                                 offsets, csr, out, ctx_sum);
    ctx_kernel<<<1, H, 0, stream>>>(ctx_sum, W1, b1, tab);
    samp_kernel<<<1280, 256, 0, stream>>>(dom, bnd, bidx, x, xmask, tab, W2, b2, W3, out);
}